// Round 16
// baseline (263.706 us; speedup 1.0000x reference)
//
#include <hip/hip_runtime.h>
#include <stdint.h>

#define N 8192
#define C 128

typedef float f32x4 __attribute__((ext_vector_type(4)));
typedef short bf16x8 __attribute__((ext_vector_type(8)));

__device__ __forceinline__ float wred(float v){
#pragma unroll
  for(int o=32;o;o>>=1) v += __shfl_xor(v,o);
  return v;
}
__device__ __forceinline__ unsigned short f2bf(float x){
  union{float f; unsigned u;} c; c.f = x;
  unsigned u = c.u;
  u += 0x7fffu + ((u>>16)&1u);
  return (unsigned short)(u>>16);
}
__device__ __forceinline__ float bf2f(unsigned short h){
  union{unsigned u; float f;} c; c.u = ((unsigned)h) << 16;
  return c.f;
}
__device__ __forceinline__ float lrelu(float z){ return z>0.f ? z : 0.01f*z; }

// ---------------- K0: adj -> bitmask (pure stream, no deps) ----------------
// maskG layout: [i][1024] bytes; byte b covers cols [b*8, b*8+8)
__global__ void k_mask(const float* __restrict__ adj, unsigned char* __restrict__ maskG){
  int tid = blockIdx.x*256 + threadIdx.x;
#pragma unroll
  for(int it=0; it<16; ++it){
    int b = tid + it*524288;                 // byte index in [0, 8M)
    int i = b >> 10;
    int j0 = (b & 1023) << 3;
    const float4* ap = (const float4*)(adj + (size_t)i*N + j0);
    float4 a0 = ap[0], a1 = ap[1];
    float av[8] = {a0.x,a0.y,a0.z,a0.w, a1.x,a1.y,a1.z,a1.w};
    unsigned mb = 0;
#pragma unroll
    for(int tt=0; tt<8; ++tt)
      mb |= ((unsigned)((av[tt] > 0.f) || (j0+tt == i))) << tt;
    maskG[b] = (unsigned char)mb;
  }
}

// ---------------- K1: fused LN1 + xn@W0 + hB fragments + hl/hr ----------------
__global__ void k_front(const float* __restrict__ x, const float* __restrict__ g1,
                        const float* __restrict__ b1, const float* __restrict__ W0,
                        const float* __restrict__ a, unsigned short* __restrict__ hB,
                        float* __restrict__ hl, float* __restrict__ hr){
  __shared__ __align__(16) float xn[32*132];
  __shared__ __align__(16) float ws[C*C];
  __shared__ __align__(16) float hs[32*C];
  int t = threadIdx.x, l = t & 63, w = t >> 6;
  int r0 = blockIdx.x*32;
#pragma unroll
  for(int p=0;p<8;p++){
    int row = p*4 + w;
    const float2 xv = *(const float2*)(x + (size_t)(r0+row)*C + l*2);
    float mu = wred(xv.x + xv.y) * (1.f/C);
    float dx = xv.x - mu, dy = xv.y - mu;
    float var = wred(dx*dx + dy*dy) * (1.f/C);
    float rs = rsqrtf(var + 1e-5f);
    const float2 gv = *(const float2*)(g1 + l*2);
    const float2 bv = *(const float2*)(b1 + l*2);
    xn[row*132 + l*2]     = dx*rs*gv.x + bv.x;
    xn[row*132 + l*2 + 1] = dy*rs*gv.y + bv.y;
  }
  int cq = t & 31, rq = t >> 5;
  for(int k=0;k<2;k++){
    __syncthreads();
    const float4* wsrc = (const float4*)(W0 + (size_t)k*C*C);
    float4* wdst = (float4*)ws;
#pragma unroll
    for(int r=0;r<16;r++) wdst[t + r*256] = wsrc[t + r*256];
    __syncthreads();
    float4 acc[4] = {};
    const float4* ws4 = (const float4*)ws;
#pragma unroll 4
    for(int kk=0; kk<C; ++kk){
      float4 wv = ws4[kk*32 + cq];
#pragma unroll
      for(int r=0;r<4;r++){
        float xv = xn[(rq*4+r)*132 + kk];
        acc[r].x += xv*wv.x; acc[r].y += xv*wv.y; acc[r].z += xv*wv.z; acc[r].w += xv*wv.w;
      }
    }
    const float4 al = *(const float4*)(a + k*2*C + cq*4);
    const float4 ar = *(const float4*)(a + k*2*C + C + cq*4);
#pragma unroll
    for(int r=0;r<4;r++){
      float sl = acc[r].x*al.x + acc[r].y*al.y + acc[r].z*al.z + acc[r].w*al.w;
      float sr = acc[r].x*ar.x + acc[r].y*ar.y + acc[r].z*ar.z + acc[r].w*ar.w;
#pragma unroll
      for(int o=16;o;o>>=1){ sl += __shfl_xor(sl,o); sr += __shfl_xor(sr,o); }
      if(cq==0){
        hl[k*N + r0 + rq*4 + r] = sl;
        hr[k*N + r0 + rq*4 + r] = sr;
      }
    }
#pragma unroll
    for(int r=0;r<4;r++) *(float4*)(hs + (rq*4+r)*C + cq*4) = acc[r];
    __syncthreads();
    unsigned short tv[16];
#pragma unroll
    for(int q=0;q<16;q++){
      int f = t*16 + q;
      int cb = f>>9, l2 = (f>>3)&63, tt = f&7;
      tv[q] = f2bf(hs[((l2>>4)*8 + tt)*C + cb*16 + (l2&15)]);
    }
    uint4* dst = (uint4*)(hB + (size_t)(k*256 + blockIdx.x)*4096 + t*16);
    dst[0] = *(uint4*)&tv[0];
    dst[1] = *(uint4*)&tv[8];
  }
}

// ---------------- K2: denominators from mask (exp-bound, tiny traffic) ----------------
__global__ void k_denom2(const unsigned char* __restrict__ maskG, const float* __restrict__ hl,
                         const float* __restrict__ hr, float* __restrict__ invd){
  int t = threadIdx.x, l = t & 63, w = t >> 6;
  int i = blockIdx.x*8 + w;
  float hl0 = hl[i], hl1 = hl[N+i];
  const unsigned char* mrow = maskG + (size_t)i*1024;
  float s0 = 0.f, s1 = 0.f;
  for(int it=0; it<16; ++it){
    unsigned mb = mrow[it*64 + l];
    int j0 = (it*64 + l)*8;
    float4 h00 = *(const float4*)(hr + j0);
    float4 h01 = *(const float4*)(hr + j0 + 4);
    float4 h10 = *(const float4*)(hr + N + j0);
    float4 h11 = *(const float4*)(hr + N + j0 + 4);
    float h0v[8] = {h00.x,h00.y,h00.z,h00.w, h01.x,h01.y,h01.z,h01.w};
    float h1v[8] = {h10.x,h10.y,h10.z,h10.w, h11.x,h11.y,h11.z,h11.w};
#pragma unroll
    for(int tt=0; tt<8; ++tt){
      bool m = (mb >> tt) & 1;
      float e0 = __expf(lrelu(hl0 + h0v[tt]));
      float e1 = __expf(lrelu(hl1 + h1v[tt]));
      s0 += m ? e0 : 0.f;
      s1 += m ? e1 : 0.f;
    }
  }
  s0 = wred(s0); s1 = wred(s1);
  if(l==0){ invd[i] = 1.f/s0; invd[N+i] = 1.f/s1; }
}

// ---------------- K3: main fused pass (R7 structure; pvp stored bf16) ----------------
// grid (64 rowtiles, 8 chunks), block 512 (8 waves x 16 rows)
__global__ __launch_bounds__(512, 4)
void k_main(const unsigned char* __restrict__ maskG, const float* __restrict__ hl,
            const float* __restrict__ hr, const float* __restrict__ invd,
            const unsigned short* __restrict__ hB,
            float* __restrict__ agg, unsigned short* __restrict__ pvp){
  __shared__ __align__(16) uint4 hBs[2][1024];          // 32 KiB double buffer
  __shared__ __align__(16) float hrs[2048];             // 8 KiB
  __shared__ __align__(16) unsigned char mlds[128*144]; // 18 KiB [row][144]
  int t = threadIdx.x, l = t & 63, w = t >> 6;          // w in 0..7
  int r0 = blockIdx.x*128, ch = blockIdx.y;
  int g = l >> 4;
  int lr = w*16 + (l & 15);                             // 0..127
  int i = r0 + lr;
  // one-time stage: hr slice (8KB) + mask tile (16KB), both coalesced
  {
    int f0 = t*4, k0 = f0 >> 10, j0 = f0 & 1023;
    *(float4*)(hrs + f0) = *(const float4*)(hr + k0*N + ch*1024 + j0);
    const uint4* msrc = (const uint4*)(maskG + (size_t)(r0 + (t>>2))*1024 + ch*128 + (t&3)*32);
    uint4* mdst = (uint4*)(mlds + (t>>2)*144 + (t&3)*32);
    mdst[0] = msrc[0];
    mdst[1] = msrc[1];
  }
  float hl0 = hl[i], hl1 = hl[N+i];
  float id0 = invd[i], id1 = invd[N+i];
  float* grow = agg + (size_t)i*N;
  const uint4* hBu = (const uint4*)hB;
  f32x4 acc[2][8] = {};
  // prefetch js=0 tile into regs
  uint4 s0v, s1v;
  {
    size_t jn = (size_t)(ch*32)*512;
    s0v = hBu[jn + t];
    s1v = hBu[131072 + jn + t];
  }
  __syncthreads();
  int cur = 0;
  for(int js=0; js<32; ++js){
    int jblk = ch*32 + js;
    // commit prefetched tile to LDS buf `cur`
    uint4* dstb = &hBs[cur][0];
    dstb[t      ] = s0v;
    dstb[t + 512] = s1v;
    // issue next tile's loads (in flight across compute)
    if(js < 31){
      size_t jn = (size_t)(jblk+1)*512;
      s0v = hBu[jn + t];
      s1v = hBu[131072 + jn + t];
    }
    __syncthreads();
    int jb = jblk*32 + g*8;
    int jl = js*32 + g*8;
    float4 h00 = *(const float4*)(hrs + jl);
    float4 h01 = *(const float4*)(hrs + jl + 4);
    float4 h10 = *(const float4*)(hrs + 1024 + jl);
    float4 h11 = *(const float4*)(hrs + 1024 + jl + 4);
    unsigned mb = mlds[lr*144 + js*4 + g];
    float h0v[8] = {h00.x,h00.y,h00.z,h00.w, h01.x,h01.y,h01.z,h01.w};
    float h1v[8] = {h10.x,h10.y,h10.z,h10.w, h11.x,h11.y,h11.z,h11.w};
    float p0[8], p1[8];
#pragma unroll
    for(int tt=0; tt<8; ++tt){
      bool m = (mb >> tt) & 1;
      float e0 = __expf(lrelu(hl0 + h0v[tt]));
      float e1 = __expf(lrelu(hl1 + h1v[tt]));
      p0[tt] = m ? e0 : 0.f;
      p1[tt] = m ? e1 : 0.f;
    }
    float4 g0, g1;
    g0.x = (p0[0]*id0 + p1[0]*id1)*0.5f;
    g0.y = (p0[1]*id0 + p1[1]*id1)*0.5f;
    g0.z = (p0[2]*id0 + p1[2]*id1)*0.5f;
    g0.w = (p0[3]*id0 + p1[3]*id1)*0.5f;
    g1.x = (p0[4]*id0 + p1[4]*id1)*0.5f;
    g1.y = (p0[5]*id0 + p1[5]*id1)*0.5f;
    g1.z = (p0[6]*id0 + p1[6]*id1)*0.5f;
    g1.w = (p0[7]*id0 + p1[7]*id1)*0.5f;
    *(float4*)(grow + jb)     = g0;
    *(float4*)(grow + jb + 4) = g1;
    union { bf16x8 v; unsigned u[4]; } fu0, fu1;
#pragma unroll
    for(int q=0;q<4;q++){
      asm("v_cvt_pk_bf16_f32 %0, %1, %2" : "=v"(fu0.u[q]) : "v"(p0[2*q]), "v"(p0[2*q+1]));
      asm("v_cvt_pk_bf16_f32 %0, %1, %2" : "=v"(fu1.u[q]) : "v"(p1[2*q]), "v"(p1[2*q+1]));
    }
    const unsigned short* bptr = (const unsigned short*)&hBs[cur][0];
#pragma unroll
    for(int cb=0; cb<8; ++cb){
      bf16x8 b0 = *(const bf16x8*)(bptr + (cb*64 + l)*8);
      bf16x8 b1 = *(const bf16x8*)(bptr + 4096 + (cb*64 + l)*8);
      acc[0][cb] = __builtin_amdgcn_mfma_f32_16x16x32_bf16(fu0.v, b0, acc[0][cb], 0, 0, 0);
      acc[1][cb] = __builtin_amdgcn_mfma_f32_16x16x32_bf16(fu1.v, b1, acc[1][cb], 0, 0, 0);
    }
    __syncthreads();
    cur ^= 1;
  }
  // write PV partials as bf16: D layout row=(l>>4)*4+r, col=lane&15
#pragma unroll
  for(int k=0;k<2;k++)
#pragma unroll
    for(int cb=0;cb<8;cb++)
#pragma unroll
      for(int r=0;r<4;r++){
        int ig = r0 + w*16 + ((l>>4)<<2) + r;
        int c = cb*16 + (l & 15);
        pvp[(size_t)((ch*2 + k)*N + ig)*C + c] = f2bf(acc[k][cb][r]);
      }
}

// ---------------- K4: reduce partials (bf16), +x, LN2 -> tmp ----------------
__global__ void k_reduce_ln(const unsigned short* __restrict__ pvp, const float* __restrict__ invd,
                            const float* __restrict__ x, const float* __restrict__ g2,
                            const float* __restrict__ b2, float* __restrict__ tmp){
  int l = threadIdx.x & 63, w = threadIdx.x >> 6;
  int wid = blockIdx.x*4 + w;
  int k = wid >> 13, i = wid & (N-1);
  float s0 = 0.f, s1 = 0.f;
#pragma unroll
  for(int ch=0; ch<8; ++ch){
    const ushort2 v = *(const ushort2*)(pvp + (size_t)((ch*2+k)*N + i)*C + l*2);
    s0 += bf2f(v.x); s1 += bf2f(v.y);
  }
  float idv = invd[k*N + i];
  const float2 xv = *(const float2*)(x + (size_t)i*C + l*2);
  float a0 = s0*idv + xv.x, a1 = s1*idv + xv.y;
  float mu = wred(a0 + a1) * (1.f/C);
  float d0 = a0 - mu, d1 = a1 - mu;
  float var = wred(d0*d0 + d1*d1) * (1.f/C);
  float rs = rsqrtf(var + 1e-5f);
  const float2 gv = *(const float2*)(g2 + l*2);
  const float2 bv = *(const float2*)(b2 + l*2);
  float2 o; o.x = d0*rs*gv.x + bv.x; o.y = d1*rs*gv.y + bv.y;
  *(float2*)(tmp + (size_t)k*N*C + (size_t)i*C + l*2) = o;
}

// ---------------- K5: h_next = sum_k elu(tmp_k @ W1[k]) / 2 ----------------
__global__ void k_out(const float* __restrict__ tmp, const float* __restrict__ W1,
                      float* __restrict__ out){
  __shared__ __align__(16) float ws[C*C];
  __shared__ __align__(16) float xs[32*132];
  int t = threadIdx.x, r0 = blockIdx.x*32;
  int cq = t & 31, rq = t >> 5;
  float oacc[4][4] = {};
  for(int k=0;k<2;k++){
    __syncthreads();
    const float4* wsrc = (const float4*)(W1 + (size_t)k*C*C);
    float4* wdst = (float4*)ws;
#pragma unroll
    for(int r=0;r<16;r++) wdst[t + r*256] = wsrc[t + r*256];
    const float4* xsrc = (const float4*)(tmp + (size_t)k*N*C + (size_t)r0*C);
#pragma unroll
    for(int r=0;r<4;r++){
      int f = t + r*256;
      int row = f >> 5, c4 = f & 31;
      *(float4*)(xs + row*132 + c4*4) = xsrc[f];
    }
    __syncthreads();
    float4 acc[4] = {};
    const float4* ws4 = (const float4*)ws;
#pragma unroll 4
    for(int kk=0; kk<C; ++kk){
      float4 wv = ws4[kk*32 + cq];
#pragma unroll
      for(int r=0;r<4;r++){
        float xv = xs[(rq*4+r)*132 + kk];
        acc[r].x += xv*wv.x; acc[r].y += xv*wv.y; acc[r].z += xv*wv.z; acc[r].w += xv*wv.w;
      }
    }
#pragma unroll
    for(int r=0;r<4;r++){
      float* ac = (float*)&acc[r];
#pragma unroll
      for(int cc=0;cc<4;cc++){
        float v = ac[cc];
        v = v > 0.f ? v : (__expf(v) - 1.f);
        oacc[r][cc] += 0.5f*v;
      }
    }
  }
#pragma unroll
  for(int r=0;r<4;r++){
    float4 o = make_float4(oacc[r][0], oacc[r][1], oacc[r][2], oacc[r][3]);
    *(float4*)(out + (size_t)(r0+rq*4+r)*C + cq*4) = o;
  }
}

extern "C" void kernel_launch(void* const* d_in, const int* in_sizes, int n_in,
                              void* d_out, int out_size, void* d_ws, size_t ws_size,
                              hipStream_t stream){
  const float* x   = (const float*)d_in[0];
  const float* adj = (const float*)d_in[1];
  const float* W0  = (const float*)d_in[2];
  const float* W1  = (const float*)d_in[3];
  const float* a   = (const float*)d_in[4];
  const float* g1  = (const float*)d_in[5];
  const float* b1  = (const float*)d_in[6];
  const float* g2  = (const float*)d_in[7];
  const float* b2  = (const float*)d_in[8];
  float* out = (float*)d_out;
  float* ws  = (float*)d_ws;

  unsigned short* hB = (unsigned short*)ws;            // 4 MB
  float* hl   = ws + 1048576;
  float* hr   = ws + 1064960;
  float* invd = ws + 1081344;
  float* tmp  = ws + 1097728;                          // 8 MB
  unsigned short* pvp = (unsigned short*)(ws + 3194880); // 32 MB as bf16
  unsigned char* maskG = (unsigned char*)(ws + 19972096); // 8 MB
  float* agg  = out + (size_t)N*C;

  k_mask     <<<2048, 256, 0, stream>>>(adj, maskG);
  k_front    <<<N/32, 256, 0, stream>>>(x, g1, b1, W0, a, hB, hl, hr);
  k_denom2   <<<N/8, 512, 0, stream>>>(maskG, hl, hr, invd);
  k_main     <<<dim3(64, 8), 512, 0, stream>>>(maskG, hl, hr, invd, hB, agg, pvp);
  k_reduce_ln<<<(2*N)/4, 256, 0, stream>>>(pvp, invd, x, g2, b2, tmp);
  k_out      <<<N/32, 256, 0, stream>>>(tmp, W1, out);
}

// Round 17
// 254.634 us; speedup vs baseline: 1.0356x; 1.0356x over previous
//
#include <hip/hip_runtime.h>
#include <stdint.h>

#define N 8192
#define C 128

typedef float f32x4 __attribute__((ext_vector_type(4)));
typedef short bf16x8 __attribute__((ext_vector_type(8)));

__device__ __forceinline__ float wred(float v){
#pragma unroll
  for(int o=32;o;o>>=1) v += __shfl_xor(v,o);
  return v;
}
__device__ __forceinline__ unsigned short f2bf(float x){
  union{float f; unsigned u;} c; c.f = x;
  unsigned u = c.u;
  u += 0x7fffu + ((u>>16)&1u);
  return (unsigned short)(u>>16);
}
__device__ __forceinline__ float bf2f(unsigned short h){
  union{unsigned u; float f;} c; c.u = ((unsigned)h) << 16;
  return c.f;
}
__device__ __forceinline__ float lrelu(float z){ return z>0.f ? z : 0.01f*z; }

// ---------------- K1: fused LN1 + xn@W0 + hB fragments + hl/hr ----------------
__global__ void k_front(const float* __restrict__ x, const float* __restrict__ g1,
                        const float* __restrict__ b1, const float* __restrict__ W0,
                        const float* __restrict__ a, unsigned short* __restrict__ hB,
                        float* __restrict__ hl, float* __restrict__ hr){
  __shared__ __align__(16) float xn[32*132];
  __shared__ __align__(16) float ws[C*C];
  __shared__ __align__(16) float hs[32*C];
  int t = threadIdx.x, l = t & 63, w = t >> 6;
  int r0 = blockIdx.x*32;
#pragma unroll
  for(int p=0;p<8;p++){
    int row = p*4 + w;
    const float2 xv = *(const float2*)(x + (size_t)(r0+row)*C + l*2);
    float mu = wred(xv.x + xv.y) * (1.f/C);
    float dx = xv.x - mu, dy = xv.y - mu;
    float var = wred(dx*dx + dy*dy) * (1.f/C);
    float rs = rsqrtf(var + 1e-5f);
    const float2 gv = *(const float2*)(g1 + l*2);
    const float2 bv = *(const float2*)(b1 + l*2);
    xn[row*132 + l*2]     = dx*rs*gv.x + bv.x;
    xn[row*132 + l*2 + 1] = dy*rs*gv.y + bv.y;
  }
  int cq = t & 31, rq = t >> 5;
  for(int k=0;k<2;k++){
    __syncthreads();
    const float4* wsrc = (const float4*)(W0 + (size_t)k*C*C);
    float4* wdst = (float4*)ws;
#pragma unroll
    for(int r=0;r<16;r++) wdst[t + r*256] = wsrc[t + r*256];
    __syncthreads();
    float4 acc[4] = {};
    const float4* ws4 = (const float4*)ws;
#pragma unroll 4
    for(int kk=0; kk<C; ++kk){
      float4 wv = ws4[kk*32 + cq];
#pragma unroll
      for(int r=0;r<4;r++){
        float xv = xn[(rq*4+r)*132 + kk];
        acc[r].x += xv*wv.x; acc[r].y += xv*wv.y; acc[r].z += xv*wv.z; acc[r].w += xv*wv.w;
      }
    }
    const float4 al = *(const float4*)(a + k*2*C + cq*4);
    const float4 ar = *(const float4*)(a + k*2*C + C + cq*4);
#pragma unroll
    for(int r=0;r<4;r++){
      float sl = acc[r].x*al.x + acc[r].y*al.y + acc[r].z*al.z + acc[r].w*al.w;
      float sr = acc[r].x*ar.x + acc[r].y*ar.y + acc[r].z*ar.z + acc[r].w*ar.w;
#pragma unroll
      for(int o=16;o;o>>=1){ sl += __shfl_xor(sl,o); sr += __shfl_xor(sr,o); }
      if(cq==0){
        hl[k*N + r0 + rq*4 + r] = sl;
        hr[k*N + r0 + rq*4 + r] = sr;
      }
    }
#pragma unroll
    for(int r=0;r<4;r++) *(float4*)(hs + (rq*4+r)*C + cq*4) = acc[r];
    __syncthreads();
    unsigned short tv[16];
#pragma unroll
    for(int q=0;q<16;q++){
      int f = t*16 + q;
      int cb = f>>9, l2 = (f>>3)&63, tt = f&7;
      tv[q] = f2bf(hs[((l2>>4)*8 + tt)*C + cb*16 + (l2&15)]);
    }
    uint4* dst = (uint4*)(hB + (size_t)(k*256 + blockIdx.x)*4096 + t*16);
    dst[0] = *(uint4*)&tv[0];
    dst[1] = *(uint4*)&tv[8];
  }
}

// ---------------- K2: denominators + bitmask (single adj pass) ----------------
// maskG layout: [i][1024] bytes; byte b of row i covers cols [b*8, b*8+8)
__global__ void k_denom(const float* __restrict__ adj, const float* __restrict__ hl,
                        const float* __restrict__ hr, float* __restrict__ invd,
                        unsigned char* __restrict__ maskG){
  int t = threadIdx.x, l = t & 63, w = t >> 6;
  int i = blockIdx.x*8 + w;
  float hl0 = hl[i], hl1 = hl[N+i];
  const float4* arow = (const float4*)(adj + (size_t)i*N);
  float s0 = 0.f, s1 = 0.f;
  for(int it=0; it<16; ++it){
    int j0 = it*512 + l*8;
    float4 a0 = arow[j0/4], a1 = arow[j0/4 + 1];
    float4 h00 = *(const float4*)(hr + j0);
    float4 h01 = *(const float4*)(hr + j0 + 4);
    float4 h10 = *(const float4*)(hr + N + j0);
    float4 h11 = *(const float4*)(hr + N + j0 + 4);
    float av[8]  = {a0.x,a0.y,a0.z,a0.w, a1.x,a1.y,a1.z,a1.w};
    float h0v[8] = {h00.x,h00.y,h00.z,h00.w, h01.x,h01.y,h01.z,h01.w};
    float h1v[8] = {h10.x,h10.y,h10.z,h10.w, h11.x,h11.y,h11.z,h11.w};
    unsigned mb = 0;
#pragma unroll
    for(int tt=0; tt<8; ++tt){
      bool m = (av[tt] > 0.f) || (j0+tt == i);
      mb |= ((unsigned)m) << tt;
      float e0 = __expf(lrelu(hl0 + h0v[tt]));
      float e1 = __expf(lrelu(hl1 + h1v[tt]));
      s0 += m ? e0 : 0.f;
      s1 += m ? e1 : 0.f;
    }
    maskG[(size_t)i*1024 + it*64 + l] = (unsigned char)mb;
  }
  s0 = wred(s0); s1 = wred(s1);
  if(l==0){ invd[i] = 1.f/s0; invd[N+i] = 1.f/s1; }
}

// ---------------- K3: main fused pass (R7 structure; pvp stored bf16) ----------------
// grid (64 rowtiles, 8 chunks), block 512 (8 waves x 16 rows)
__global__ __launch_bounds__(512, 4)
void k_main(const unsigned char* __restrict__ maskG, const float* __restrict__ hl,
            const float* __restrict__ hr, const float* __restrict__ invd,
            const unsigned short* __restrict__ hB,
            float* __restrict__ agg, unsigned short* __restrict__ pvp){
  __shared__ __align__(16) uint4 hBs[2][1024];          // 32 KiB double buffer
  __shared__ __align__(16) float hrs[2048];             // 8 KiB
  __shared__ __align__(16) unsigned char mlds[128*144]; // 18 KiB [row][144]
  int t = threadIdx.x, l = t & 63, w = t >> 6;          // w in 0..7
  int r0 = blockIdx.x*128, ch = blockIdx.y;
  int g = l >> 4;
  int lr = w*16 + (l & 15);                             // 0..127
  int i = r0 + lr;
  // one-time stage: hr slice (8KB) + mask tile (16KB), both coalesced
  {
    int f0 = t*4, k0 = f0 >> 10, j0 = f0 & 1023;
    *(float4*)(hrs + f0) = *(const float4*)(hr + k0*N + ch*1024 + j0);
    const uint4* msrc = (const uint4*)(maskG + (size_t)(r0 + (t>>2))*1024 + ch*128 + (t&3)*32);
    uint4* mdst = (uint4*)(mlds + (t>>2)*144 + (t&3)*32);
    mdst[0] = msrc[0];
    mdst[1] = msrc[1];
  }
  float hl0 = hl[i], hl1 = hl[N+i];
  float id0 = invd[i], id1 = invd[N+i];
  float* grow = agg + (size_t)i*N;
  const uint4* hBu = (const uint4*)hB;
  f32x4 acc[2][8] = {};
  // prefetch js=0 tile into regs
  uint4 s0v, s1v;
  {
    size_t jn = (size_t)(ch*32)*512;
    s0v = hBu[jn + t];
    s1v = hBu[131072 + jn + t];
  }
  __syncthreads();
  int cur = 0;
  for(int js=0; js<32; ++js){
    int jblk = ch*32 + js;
    // commit prefetched tile to LDS buf `cur`
    uint4* dstb = &hBs[cur][0];
    dstb[t      ] = s0v;
    dstb[t + 512] = s1v;
    // issue next tile's loads (in flight across compute)
    if(js < 31){
      size_t jn = (size_t)(jblk+1)*512;
      s0v = hBu[jn + t];
      s1v = hBu[131072 + jn + t];
    }
    __syncthreads();
    int jb = jblk*32 + g*8;
    int jl = js*32 + g*8;
    float4 h00 = *(const float4*)(hrs + jl);
    float4 h01 = *(const float4*)(hrs + jl + 4);
    float4 h10 = *(const float4*)(hrs + 1024 + jl);
    float4 h11 = *(const float4*)(hrs + 1024 + jl + 4);
    unsigned mb = mlds[lr*144 + js*4 + g];
    float h0v[8] = {h00.x,h00.y,h00.z,h00.w, h01.x,h01.y,h01.z,h01.w};
    float h1v[8] = {h10.x,h10.y,h10.z,h10.w, h11.x,h11.y,h11.z,h11.w};
    float p0[8], p1[8];
#pragma unroll
    for(int tt=0; tt<8; ++tt){
      bool m = (mb >> tt) & 1;
      float e0 = __expf(lrelu(hl0 + h0v[tt]));
      float e1 = __expf(lrelu(hl1 + h1v[tt]));
      p0[tt] = m ? e0 : 0.f;
      p1[tt] = m ? e1 : 0.f;
    }
    float4 g0, g1;
    g0.x = (p0[0]*id0 + p1[0]*id1)*0.5f;
    g0.y = (p0[1]*id0 + p1[1]*id1)*0.5f;
    g0.z = (p0[2]*id0 + p1[2]*id1)*0.5f;
    g0.w = (p0[3]*id0 + p1[3]*id1)*0.5f;
    g1.x = (p0[4]*id0 + p1[4]*id1)*0.5f;
    g1.y = (p0[5]*id0 + p1[5]*id1)*0.5f;
    g1.z = (p0[6]*id0 + p1[6]*id1)*0.5f;
    g1.w = (p0[7]*id0 + p1[7]*id1)*0.5f;
    *(float4*)(grow + jb)     = g0;
    *(float4*)(grow + jb + 4) = g1;
    union { bf16x8 v; unsigned u[4]; } fu0, fu1;
#pragma unroll
    for(int q=0;q<4;q++){
      asm("v_cvt_pk_bf16_f32 %0, %1, %2" : "=v"(fu0.u[q]) : "v"(p0[2*q]), "v"(p0[2*q+1]));
      asm("v_cvt_pk_bf16_f32 %0, %1, %2" : "=v"(fu1.u[q]) : "v"(p1[2*q]), "v"(p1[2*q+1]));
    }
    const unsigned short* bptr = (const unsigned short*)&hBs[cur][0];
#pragma unroll
    for(int cb=0; cb<8; ++cb){
      bf16x8 b0 = *(const bf16x8*)(bptr + (cb*64 + l)*8);
      bf16x8 b1 = *(const bf16x8*)(bptr + 4096 + (cb*64 + l)*8);
      acc[0][cb] = __builtin_amdgcn_mfma_f32_16x16x32_bf16(fu0.v, b0, acc[0][cb], 0, 0, 0);
      acc[1][cb] = __builtin_amdgcn_mfma_f32_16x16x32_bf16(fu1.v, b1, acc[1][cb], 0, 0, 0);
    }
    __syncthreads();
    cur ^= 1;
  }
  // write PV partials as bf16: D layout row=(l>>4)*4+r, col=lane&15
#pragma unroll
  for(int k=0;k<2;k++)
#pragma unroll
    for(int cb=0;cb<8;cb++)
#pragma unroll
      for(int r=0;r<4;r++){
        int ig = r0 + w*16 + ((l>>4)<<2) + r;
        int c = cb*16 + (l & 15);
        pvp[(size_t)((ch*2 + k)*N + ig)*C + c] = f2bf(acc[k][cb][r]);
      }
}

// ---------------- K4: reduce partials (bf16), +x, LN2 -> tmp ----------------
__global__ void k_reduce_ln(const unsigned short* __restrict__ pvp, const float* __restrict__ invd,
                            const float* __restrict__ x, const float* __restrict__ g2,
                            const float* __restrict__ b2, float* __restrict__ tmp){
  int l = threadIdx.x & 63, w = threadIdx.x >> 6;
  int wid = blockIdx.x*4 + w;
  int k = wid >> 13, i = wid & (N-1);
  float s0 = 0.f, s1 = 0.f;
#pragma unroll
  for(int ch=0; ch<8; ++ch){
    const ushort2 v = *(const ushort2*)(pvp + (size_t)((ch*2+k)*N + i)*C + l*2);
    s0 += bf2f(v.x); s1 += bf2f(v.y);
  }
  float idv = invd[k*N + i];
  const float2 xv = *(const float2*)(x + (size_t)i*C + l*2);
  float a0 = s0*idv + xv.x, a1 = s1*idv + xv.y;
  float mu = wred(a0 + a1) * (1.f/C);
  float d0 = a0 - mu, d1 = a1 - mu;
  float var = wred(d0*d0 + d1*d1) * (1.f/C);
  float rs = rsqrtf(var + 1e-5f);
  const float2 gv = *(const float2*)(g2 + l*2);
  const float2 bv = *(const float2*)(b2 + l*2);
  float2 o; o.x = d0*rs*gv.x + bv.x; o.y = d1*rs*gv.y + bv.y;
  *(float2*)(tmp + (size_t)k*N*C + (size_t)i*C + l*2) = o;
}

// ---------------- K5: h_next = sum_k elu(tmp_k @ W1[k]) / 2 ----------------
__global__ void k_out(const float* __restrict__ tmp, const float* __restrict__ W1,
                      float* __restrict__ out){
  __shared__ __align__(16) float ws[C*C];
  __shared__ __align__(16) float xs[32*132];
  int t = threadIdx.x, r0 = blockIdx.x*32;
  int cq = t & 31, rq = t >> 5;
  float oacc[4][4] = {};
  for(int k=0;k<2;k++){
    __syncthreads();
    const float4* wsrc = (const float4*)(W1 + (size_t)k*C*C);
    float4* wdst = (float4*)ws;
#pragma unroll
    for(int r=0;r<16;r++) wdst[t + r*256] = wsrc[t + r*256];
    const float4* xsrc = (const float4*)(tmp + (size_t)k*N*C + (size_t)r0*C);
#pragma unroll
    for(int r=0;r<4;r++){
      int f = t + r*256;
      int row = f >> 5, c4 = f & 31;
      *(float4*)(xs + row*132 + c4*4) = xsrc[f];
    }
    __syncthreads();
    float4 acc[4] = {};
    const float4* ws4 = (const float4*)ws;
#pragma unroll 4
    for(int kk=0; kk<C; ++kk){
      float4 wv = ws4[kk*32 + cq];
#pragma unroll
      for(int r=0;r<4;r++){
        float xv = xs[(rq*4+r)*132 + kk];
        acc[r].x += xv*wv.x; acc[r].y += xv*wv.y; acc[r].z += xv*wv.z; acc[r].w += xv*wv.w;
      }
    }
#pragma unroll
    for(int r=0;r<4;r++){
      float* ac = (float*)&acc[r];
#pragma unroll
      for(int cc=0;cc<4;cc++){
        float v = ac[cc];
        v = v > 0.f ? v : (__expf(v) - 1.f);
        oacc[r][cc] += 0.5f*v;
      }
    }
  }
#pragma unroll
  for(int r=0;r<4;r++){
    float4 o = make_float4(oacc[r][0], oacc[r][1], oacc[r][2], oacc[r][3]);
    *(float4*)(out + (size_t)(r0+rq*4+r)*C + cq*4) = o;
  }
}

extern "C" void kernel_launch(void* const* d_in, const int* in_sizes, int n_in,
                              void* d_out, int out_size, void* d_ws, size_t ws_size,
                              hipStream_t stream){
  const float* x   = (const float*)d_in[0];
  const float* adj = (const float*)d_in[1];
  const float* W0  = (const float*)d_in[2];
  const float* W1  = (const float*)d_in[3];
  const float* a   = (const float*)d_in[4];
  const float* g1  = (const float*)d_in[5];
  const float* b1  = (const float*)d_in[6];
  const float* g2  = (const float*)d_in[7];
  const float* b2  = (const float*)d_in[8];
  float* out = (float*)d_out;
  float* ws  = (float*)d_ws;

  unsigned short* hB = (unsigned short*)ws;            // 4 MB
  float* hl   = ws + 1048576;
  float* hr   = ws + 1064960;
  float* invd = ws + 1081344;
  float* tmp  = ws + 1097728;                          // 8 MB
  unsigned short* pvp = (unsigned short*)(ws + 3194880); // 32 MB as bf16
  unsigned char* maskG = (unsigned char*)(ws + 19972096); // 8 MB
  float* agg  = out + (size_t)N*C;

  k_front    <<<N/32, 256, 0, stream>>>(x, g1, b1, W0, a, hB, hl, hr);
  k_denom    <<<N/8, 512, 0, stream>>>(adj, hl, hr, invd, maskG);
  k_main     <<<dim3(64, 8), 512, 0, stream>>>(maskG, hl, hr, invd, hB, agg, pvp);
  k_reduce_ln<<<(2*N)/4, 256, 0, stream>>>(pvp, invd, x, g2, b2, tmp);
  k_out      <<<N/32, 256, 0, stream>>>(tmp, W1, out);
}